// Round 4
// baseline (263.762 us; speedup 1.0000x reference)
//
#include <hip/hip_runtime.h>

#define LN_EPS 1e-5f

static constexpr int Hc    = 512;
static constexpr int Fc    = 16;
static constexpr int Sc    = 1024;
static constexpr int NROWS = 128 * 1024;  // B*S
static constexpr int RPW   = 16;          // rows per wave

// ---- prologue: emb2[s][h] = emb[s][h] + sum_i b[i][h]  (2 MB into d_ws) ----
__global__ void emb2_kernel(const float* __restrict__ b, const float* __restrict__ emb,
                            float* __restrict__ emb2) {
    const int s = blockIdx.x;          // 1024 blocks
    const int h = threadIdx.x * 4;     // 128 threads
    float4 acc = *reinterpret_cast<const float4*>(&emb[s * Hc + h]);
#pragma unroll
    for (int i = 0; i < Fc; ++i) {
        float4 bv = *reinterpret_cast<const float4*>(&b[i * Hc + h]);
        acc.x += bv.x; acc.y += bv.y; acc.z += bv.z; acc.w += bv.w;
    }
    *reinterpret_cast<float4*>(&emb2[s * Hc + h]) = acc;
}

// ---- DPP wave64 sum: 6 VALU steps + readlane, no LDS ----
template <int CTRL, int RMASK>
__device__ __forceinline__ float dpp_add(float v) {
    int t = __builtin_amdgcn_update_dpp(0, __float_as_int(v), CTRL, RMASK, 0xf, true);
    return v + __int_as_float(t);
}
__device__ __forceinline__ float wave_sum64(float v) {
    v = dpp_add<0x111, 0xf>(v);   // row_shr:1
    v = dpp_add<0x112, 0xf>(v);   // row_shr:2
    v = dpp_add<0x114, 0xf>(v);   // row_shr:4
    v = dpp_add<0x118, 0xf>(v);   // row_shr:8  -> lane15 of each row16 has row sum
    v = dpp_add<0x142, 0xa>(v);   // row_bcast:15 into rows 1,3
    v = dpp_add<0x143, 0xc>(v);   // row_bcast:31 into rows 2,3 -> lane63 total
    return __int_as_float(__builtin_amdgcn_readlane(__float_as_int(v), 63));
}

__device__ __forceinline__ float rdlane(float v, int l) {
    return __int_as_float(__builtin_amdgcn_readlane(__float_as_int(v), l));
}

// ---- fused: one wave per row-group of 16; 8 cols/lane (h0=lane*4, h1=h0+256) ----
template <bool FOLDED>
__global__ __launch_bounds__(256, 3) void fused_kernel(
    const float* __restrict__ x, const float* __restrict__ W,
    const float* __restrict__ embp,     // FOLDED ? emb2 : emb
    const float* __restrict__ bsum,     // used only if !FOLDED (512 floats)
    const float* __restrict__ gamma, const float* __restrict__ beta,
    float* __restrict__ out)
{
    const int lane  = threadIdx.x & 63;
    const int wid   = (blockIdx.x << 2) | (threadIdx.x >> 6);
    const int rbase = wid * RPW;
    const int h0 = lane * 4, h1 = h0 + 256;
    const int s0 = rbase & (Sc - 1);    // 16 | rbase and 16 | Sc -> no wrap inside the group

    // register-resident W panel: 16 K-rows x 8 cols per lane (128 VGPR)
    float4 w0[Fc], w1[Fc];
#pragma unroll
    for (int i = 0; i < Fc; ++i) {
        w0[i] = *reinterpret_cast<const float4*>(&W[i * Hc + h0]);
        w1[i] = *reinterpret_cast<const float4*>(&W[i * Hc + h1]);
    }
    const float4 g0  = *reinterpret_cast<const float4*>(&gamma[h0]);
    const float4 g1  = *reinterpret_cast<const float4*>(&gamma[h1]);
    const float4 be0 = *reinterpret_cast<const float4*>(&beta[h0]);
    const float4 be1 = *reinterpret_cast<const float4*>(&beta[h1]);
    float4 bs0, bs1;
    if (!FOLDED) {
        bs0 = *reinterpret_cast<const float4*>(&bsum[h0]);
        bs1 = *reinterpret_cast<const float4*>(&bsum[h1]);
    }

    // x batches: one dword/lane covers 4 rows (64 floats); ping-pong, prefetch 1 batch ahead
    float xb0 = x[(size_t)rbase * Fc + lane];
    float xb1 = 0.f;

#pragma unroll
    for (int t = 0; t < RPW; ++t) {
        if ((t & 3) == 0) {
            const int nb = (t >> 2) + 1;
            if (nb < 4) {
                float v = x[(size_t)(rbase + nb * 4) * Fc + lane];
                if (nb & 1) xb1 = v; else xb0 = v;
            }
        }
        const float xsrc = ((t >> 2) & 1) ? xb1 : xb0;

        const int r = rbase + t;
        const float* e = &embp[(size_t)(s0 + t) * Hc];
        const float4 e0 = *reinterpret_cast<const float4*>(&e[h0]);
        const float4 e1 = *reinterpret_cast<const float4*>(&e[h1]);

        float xs[Fc];
#pragma unroll
        for (int i = 0; i < Fc; ++i)
            xs[i] = rdlane(xsrc, (t & 3) * 16 + i);

        // FMA tree starts from x0*w (not e) so the e-load latency hides under it
        float4 a0, a1;
        a0.x = xs[0] * w0[0].x; a0.y = xs[0] * w0[0].y; a0.z = xs[0] * w0[0].z; a0.w = xs[0] * w0[0].w;
        a1.x = xs[0] * w1[0].x; a1.y = xs[0] * w1[0].y; a1.z = xs[0] * w1[0].z; a1.w = xs[0] * w1[0].w;
#pragma unroll
        for (int i = 1; i < Fc; ++i) {
            a0.x = fmaf(xs[i], w0[i].x, a0.x);
            a0.y = fmaf(xs[i], w0[i].y, a0.y);
            a0.z = fmaf(xs[i], w0[i].z, a0.z);
            a0.w = fmaf(xs[i], w0[i].w, a0.w);
            a1.x = fmaf(xs[i], w1[i].x, a1.x);
            a1.y = fmaf(xs[i], w1[i].y, a1.y);
            a1.z = fmaf(xs[i], w1[i].z, a1.z);
            a1.w = fmaf(xs[i], w1[i].w, a1.w);
        }
        a0.x += e0.x; a0.y += e0.y; a0.z += e0.z; a0.w += e0.w;
        a1.x += e1.x; a1.y += e1.y; a1.z += e1.z; a1.w += e1.w;
        if (!FOLDED) {
            a0.x += bs0.x; a0.y += bs0.y; a0.z += bs0.z; a0.w += bs0.w;
            a1.x += bs1.x; a1.y += bs1.y; a1.z += bs1.z; a1.w += bs1.w;
        }

        float psum = a0.x + a0.y + a0.z + a0.w + a1.x + a1.y + a1.z + a1.w;
        float pssq = fmaf(a0.x, a0.x, fmaf(a0.y, a0.y, fmaf(a0.z, a0.z, a0.w * a0.w)));
        pssq = fmaf(a1.x, a1.x, fmaf(a1.y, a1.y, fmaf(a1.z, a1.z, fmaf(a1.w, a1.w, pssq))));

        const float sum = wave_sum64(psum);
        const float ssq = wave_sum64(pssq);

        const float mean = sum * (1.0f / 512.0f);
        const float var  = ssq * (1.0f / 512.0f) - mean * mean;
        const float rs   = rsqrtf(var + LN_EPS);

        float4 r0, r1;
        r0.x = (a0.x - mean) * rs * g0.x + be0.x;
        r0.y = (a0.y - mean) * rs * g0.y + be0.y;
        r0.z = (a0.z - mean) * rs * g0.z + be0.z;
        r0.w = (a0.w - mean) * rs * g0.w + be0.w;
        r1.x = (a1.x - mean) * rs * g1.x + be1.x;
        r1.y = (a1.y - mean) * rs * g1.y + be1.y;
        r1.z = (a1.z - mean) * rs * g1.z + be1.z;
        r1.w = (a1.w - mean) * rs * g1.w + be1.w;

        float* orow = out + (size_t)r * Hc;
        *reinterpret_cast<float4*>(&orow[h0]) = r0;
        *reinterpret_cast<float4*>(&orow[h1]) = r1;
    }
}

// bsum fallback prologue (only if ws too small for emb2)
__global__ void bsum_kernel(const float* __restrict__ b, float* __restrict__ bsum) {
    int h = blockIdx.x * 64 + threadIdx.x;
    float s = 0.f;
#pragma unroll
    for (int i = 0; i < Fc; ++i) s += b[i * Hc + h];
    bsum[h] = s;
}

extern "C" void kernel_launch(void* const* d_in, const int* in_sizes, int n_in,
                              void* d_out, int out_size, void* d_ws, size_t ws_size,
                              hipStream_t stream) {
    const float* x     = (const float*)d_in[0];
    const float* W     = (const float*)d_in[1];
    const float* b     = (const float*)d_in[2];
    const float* emb   = (const float*)d_in[3];
    const float* gamma = (const float*)d_in[4];
    const float* beta  = (const float*)d_in[5];
    float* out = (float*)d_out;

    const int blocks = NROWS / (RPW * 4);   // 2048 blocks x 4 waves x 16 rows

    if (ws_size >= (size_t)Sc * Hc * sizeof(float)) {
        float* emb2 = (float*)d_ws;
        emb2_kernel<<<Sc, Hc / 4, 0, stream>>>(b, emb, emb2);
        fused_kernel<true><<<blocks, 256, 0, stream>>>(x, W, emb2, nullptr, gamma, beta, out);
    } else {
        float* bsum = (float*)d_ws;   // 512 floats
        bsum_kernel<<<Hc / 64, 64, 0, stream>>>(b, bsum);
        fused_kernel<false><<<blocks, 256, 0, stream>>>(x, W, emb, bsum, gamma, beta, out);
    }
}

// Round 6
// 75.718 us; speedup vs baseline: 3.4835x; 3.4835x over previous
//
#include <hip/hip_runtime.h>

#define LN_EPS 1e-5f

typedef float f32x4 __attribute__((ext_vector_type(4)));

static constexpr int Hc    = 512;
static constexpr int Fc    = 16;
static constexpr int Sc    = 1024;
static constexpr int NROWS = 128 * 1024;  // B*S
static constexpr int RPW   = 16;          // rows per wave

// ---- prologue: emb2[s][h] = emb[s][h] + sum_i b[i][h]  (2 MB into d_ws) ----
__global__ void emb2_kernel(const float* __restrict__ b, const float* __restrict__ emb,
                            float* __restrict__ emb2) {
    const int s = blockIdx.x;          // 1024 blocks
    const int h = threadIdx.x * 4;     // 128 threads
    float4 acc = *reinterpret_cast<const float4*>(&emb[s * Hc + h]);
#pragma unroll
    for (int i = 0; i < Fc; ++i) {
        float4 bv = *reinterpret_cast<const float4*>(&b[i * Hc + h]);
        acc.x += bv.x; acc.y += bv.y; acc.z += bv.z; acc.w += bv.w;
    }
    *reinterpret_cast<float4*>(&emb2[s * Hc + h]) = acc;
}

// ---- DPP wave64 sum: 6 VALU steps + readlane, no LDS, no barriers ----
template <int CTRL, int RMASK>
__device__ __forceinline__ float dpp_add(float v) {
    int t = __builtin_amdgcn_update_dpp(0, __float_as_int(v), CTRL, RMASK, 0xf, true);
    return v + __int_as_float(t);
}
__device__ __forceinline__ float wave_sum64(float v) {
    v = dpp_add<0x111, 0xf>(v);   // row_shr:1
    v = dpp_add<0x112, 0xf>(v);   // row_shr:2
    v = dpp_add<0x114, 0xf>(v);   // row_shr:4
    v = dpp_add<0x118, 0xf>(v);   // row_shr:8  -> lane15 of each row16 has row sum
    v = dpp_add<0x142, 0xa>(v);   // row_bcast:15 into rows 1,3
    v = dpp_add<0x143, 0xc>(v);   // row_bcast:31 into row 3 -> lane63 has total
    return __int_as_float(__builtin_amdgcn_readlane(__float_as_int(v), 63));
}

__device__ __forceinline__ float rdlane(float v, int l) {
    return __int_as_float(__builtin_amdgcn_readlane(__float_as_int(v), l));
}

__device__ __forceinline__ void nt_store4(float* p, float a, float b, float c, float d) {
    f32x4 v; v.x = a; v.y = b; v.z = c; v.w = d;
    __builtin_nontemporal_store(v, reinterpret_cast<f32x4*>(p));
}

// ---- fused: one wave per 16-row group; 8 cols/lane (h0=lane*4, h1=h0+256) ----
// NOTE: no min-waves in launch_bounds — R4 showed (256,3) caps VGPR at 84 and
// spills the 128-reg W panel to scratch (FETCH/WRITE +300 MB each).
template <bool FOLDED>
__global__ __launch_bounds__(256) void fused_kernel(
    const float* __restrict__ x, const float* __restrict__ W,
    const float* __restrict__ embp,     // FOLDED ? emb2 : emb
    const float* __restrict__ bsum,     // used only if !FOLDED
    const float* __restrict__ gamma, const float* __restrict__ beta,
    float* __restrict__ out)
{
    const int lane  = threadIdx.x & 63;
    const int wid   = (blockIdx.x << 2) | (threadIdx.x >> 6);
    const int rbase = wid * RPW;
    const int h0 = lane * 4, h1 = h0 + 256;
    const int s0 = rbase & (Sc - 1);    // 16 | rbase, 16 | Sc -> no wrap inside group

    // register-resident W panel: 16 K-rows x 8 cols per lane (128 VGPR)
    float4 w0[Fc], w1[Fc];
#pragma unroll
    for (int i = 0; i < Fc; ++i) {
        w0[i] = *reinterpret_cast<const float4*>(&W[i * Hc + h0]);
        w1[i] = *reinterpret_cast<const float4*>(&W[i * Hc + h1]);
    }

    // x for all 16 rows up front: 4 coalesced dwords/lane (rows rbase+4q..+3)
    const float* xb = x + (size_t)rbase * Fc;
    float xq0 = __builtin_nontemporal_load(xb + 0 * 64 + lane);
    float xq1 = __builtin_nontemporal_load(xb + 1 * 64 + lane);
    float xq2 = __builtin_nontemporal_load(xb + 2 * 64 + lane);
    float xq3 = __builtin_nontemporal_load(xb + 3 * 64 + lane);

    const float4 g0  = *reinterpret_cast<const float4*>(&gamma[h0]);
    const float4 g1  = *reinterpret_cast<const float4*>(&gamma[h1]);
    const float4 be0 = *reinterpret_cast<const float4*>(&beta[h0]);
    const float4 be1 = *reinterpret_cast<const float4*>(&beta[h1]);
    float4 bs0, bs1;
    if (!FOLDED) {
        bs0 = *reinterpret_cast<const float4*>(&bsum[h0]);
        bs1 = *reinterpret_cast<const float4*>(&bsum[h1]);
    }

    // emb ping-pong: even t in eA, odd t in eB; prefetch t=0 now
    float4 eA0 = *reinterpret_cast<const float4*>(&embp[(size_t)s0 * Hc + h0]);
    float4 eA1 = *reinterpret_cast<const float4*>(&embp[(size_t)s0 * Hc + h1]);
    float4 eB0, eB1;

#pragma unroll
    for (int t = 0; t < RPW; ++t) {
        // prefetch e for t+1 into the other slot
        if (t < RPW - 1) {
            const float* en = &embp[(size_t)(s0 + t + 1) * Hc];
            if (t & 1) { eA0 = *reinterpret_cast<const float4*>(&en[h0]);
                         eA1 = *reinterpret_cast<const float4*>(&en[h1]); }
            else       { eB0 = *reinterpret_cast<const float4*>(&en[h0]);
                         eB1 = *reinterpret_cast<const float4*>(&en[h1]); }
        }
        const float4 ec0 = (t & 1) ? eB0 : eA0;
        const float4 ec1 = (t & 1) ? eB1 : eA1;

        const float xsrc = (t >> 2) == 0 ? xq0 : (t >> 2) == 1 ? xq1 : (t >> 2) == 2 ? xq2 : xq3;
        float xs[Fc];
#pragma unroll
        for (int i = 0; i < Fc; ++i)
            xs[i] = rdlane(xsrc, (t & 3) * 16 + i);

        // FMA tree starts from x0*w so the e-load latency hides under it
        float4 a0, a1;
        a0.x = xs[0] * w0[0].x; a0.y = xs[0] * w0[0].y; a0.z = xs[0] * w0[0].z; a0.w = xs[0] * w0[0].w;
        a1.x = xs[0] * w1[0].x; a1.y = xs[0] * w1[0].y; a1.z = xs[0] * w1[0].z; a1.w = xs[0] * w1[0].w;
#pragma unroll
        for (int i = 1; i < Fc; ++i) {
            a0.x = fmaf(xs[i], w0[i].x, a0.x);
            a0.y = fmaf(xs[i], w0[i].y, a0.y);
            a0.z = fmaf(xs[i], w0[i].z, a0.z);
            a0.w = fmaf(xs[i], w0[i].w, a0.w);
            a1.x = fmaf(xs[i], w1[i].x, a1.x);
            a1.y = fmaf(xs[i], w1[i].y, a1.y);
            a1.z = fmaf(xs[i], w1[i].z, a1.z);
            a1.w = fmaf(xs[i], w1[i].w, a1.w);
        }
        a0.x += ec0.x; a0.y += ec0.y; a0.z += ec0.z; a0.w += ec0.w;
        a1.x += ec1.x; a1.y += ec1.y; a1.z += ec1.z; a1.w += ec1.w;
        if (!FOLDED) {
            a0.x += bs0.x; a0.y += bs0.y; a0.z += bs0.z; a0.w += bs0.w;
            a1.x += bs1.x; a1.y += bs1.y; a1.z += bs1.z; a1.w += bs1.w;
        }

        float psum = a0.x + a0.y + a0.z + a0.w + a1.x + a1.y + a1.z + a1.w;
        float pssq = fmaf(a0.x, a0.x, fmaf(a0.y, a0.y, fmaf(a0.z, a0.z, a0.w * a0.w)));
        pssq = fmaf(a1.x, a1.x, fmaf(a1.y, a1.y, fmaf(a1.z, a1.z, fmaf(a1.w, a1.w, pssq))));

        const float sum = wave_sum64(psum);
        const float ssq = wave_sum64(pssq);

        const float mean = sum * (1.0f / 512.0f);
        const float var  = ssq * (1.0f / 512.0f) - mean * mean;
        const float rs   = rsqrtf(var + LN_EPS);

        // non-temporal: out is never re-read; don't thrash L2 (emb/W live there)
        float* orow = out + (size_t)(rbase + t) * Hc;
        nt_store4(&orow[h0],
                  (a0.x - mean) * rs * g0.x + be0.x,
                  (a0.y - mean) * rs * g0.y + be0.y,
                  (a0.z - mean) * rs * g0.z + be0.z,
                  (a0.w - mean) * rs * g0.w + be0.w);
        nt_store4(&orow[h1],
                  (a1.x - mean) * rs * g1.x + be1.x,
                  (a1.y - mean) * rs * g1.y + be1.y,
                  (a1.z - mean) * rs * g1.z + be1.z,
                  (a1.w - mean) * rs * g1.w + be1.w);
    }
}

// bsum fallback prologue (only if ws too small for emb2)
__global__ void bsum_kernel(const float* __restrict__ b, float* __restrict__ bsum) {
    int h = blockIdx.x * 64 + threadIdx.x;
    float s = 0.f;
#pragma unroll
    for (int i = 0; i < Fc; ++i) s += b[i * Hc + h];
    bsum[h] = s;
}

extern "C" void kernel_launch(void* const* d_in, const int* in_sizes, int n_in,
                              void* d_out, int out_size, void* d_ws, size_t ws_size,
                              hipStream_t stream) {
    const float* x     = (const float*)d_in[0];
    const float* W     = (const float*)d_in[1];
    const float* b     = (const float*)d_in[2];
    const float* emb   = (const float*)d_in[3];
    const float* gamma = (const float*)d_in[4];
    const float* beta  = (const float*)d_in[5];
    float* out = (float*)d_out;

    const int blocks = NROWS / (RPW * 4);   // 2048 blocks x 4 waves x 16 rows

    if (ws_size >= (size_t)Sc * Hc * sizeof(float)) {
        float* emb2 = (float*)d_ws;
        emb2_kernel<<<Sc, Hc / 4, 0, stream>>>(b, emb, emb2);
        fused_kernel<true><<<blocks, 256, 0, stream>>>(x, W, emb2, nullptr, gamma, beta, out);
    } else {
        float* bsum = (float*)d_ws;   // 512 floats
        bsum_kernel<<<Hc / 64, 64, 0, stream>>>(b, bsum);
        fused_kernel<false><<<blocks, 256, 0, stream>>>(x, W, emb, bsum, gamma, beta, out);
    }
}